// Round 3
// baseline (1113.091 us; speedup 1.0000x reference)
//
#include <hip/hip_runtime.h>
#include <stdint.h>

#define NN 100000
#define NE 1600000

// ---------------- CSR build ----------------
__global__ void hist_kernel(const int* __restrict__ ei, int* __restrict__ deg) {
    int e = blockIdx.x * blockDim.x + threadIdx.x;
    if (e >= NE) return;
    int d = ei[NE + e];
    atomicAdd(&deg[d], 1);
}

// per-block (1024 elems, 256 thr) exclusive scan; writes exclusive partials + block sums
__global__ void scan_partial(const int* __restrict__ deg, int* __restrict__ excl,
                             int* __restrict__ bsums) {
    __shared__ int ts[256];
    int t = threadIdx.x;
    int base = blockIdx.x * 1024 + t * 4;
    int v0 = 0, v1 = 0, v2 = 0, v3 = 0;
    if (base + 3 < NN) {
        int4 v = *(const int4*)(deg + base);
        v0 = v.x; v1 = v.y; v2 = v.z; v3 = v.w;
    } else {
        if (base + 0 < NN) v0 = deg[base + 0];
        if (base + 1 < NN) v1 = deg[base + 1];
        if (base + 2 < NN) v2 = deg[base + 2];
        if (base + 3 < NN) v3 = deg[base + 3];
    }
    int s3 = v0 + v1 + v2 + v3;
    ts[t] = s3;
    __syncthreads();
    int sum = s3;
    for (int off = 1; off < 256; off <<= 1) {
        int x = (t >= off) ? ts[t - off] : 0;
        __syncthreads();
        sum += x;
        ts[t] = sum;
        __syncthreads();
    }
    if (t == 255) bsums[blockIdx.x] = sum;
    int pre = sum - s3;  // exclusive over threads within block
    int e0 = pre, e1 = pre + v0, e2 = pre + v0 + v1, e3 = pre + v0 + v1 + v2;
    if (base + 3 < NN) {
        *(int4*)(excl + base) = make_int4(e0, e1, e2, e3);
    } else {
        if (base + 0 < NN) excl[base + 0] = e0;
        if (base + 1 < NN) excl[base + 1] = e1;
        if (base + 2 < NN) excl[base + 2] = e2;
        if (base + 3 < NN) excl[base + 3] = e3;
    }
}

__global__ void scan_sums(int* __restrict__ bsums, int nb) {  // 1 block, 128 thr
    __shared__ int ts[128];
    int t = threadIdx.x;
    int v = (t < nb) ? bsums[t] : 0;
    ts[t] = v;
    __syncthreads();
    int sum = v;
    for (int off = 1; off < 128; off <<= 1) {
        int x = (t >= off) ? ts[t - off] : 0;
        __syncthreads();
        sum += x;
        ts[t] = sum;
        __syncthreads();
    }
    if (t < nb) bsums[t] = sum - v;  // exclusive
}

__global__ void scan_finalize(const int* __restrict__ excl, const int* __restrict__ bsums,
                              int* __restrict__ rowptr, int* __restrict__ cursor) {
    int i = blockIdx.x * blockDim.x + threadIdx.x;
    if (i < NN) {
        int v = excl[i] + bsums[i >> 10];
        rowptr[i] = v;
        cursor[i] = v;
    } else if (i == NN) {
        rowptr[NN] = NE;
    }
}

__global__ void fill_kernel(const int* __restrict__ ei, int* __restrict__ cursor,
                            int* __restrict__ esrc) {
    int e = blockIdx.x * blockDim.x + threadIdx.x;
    if (e >= NE) return;
    int s = ei[e];
    int d = ei[NE + e];
    int pos = atomicAdd(&cursor[d], 1);
    esrc[pos] = s;
}

// ---------------- SPMM (segment sum), 128-wide rows ----------------
// one wave per node; lane handles 2 cols via float2; rst = x + sum_{in-edges} x[src]
__global__ void spmm128_kernel(const float* __restrict__ x, const int* __restrict__ rowptr,
                               const int* __restrict__ esrc, float* __restrict__ rst) {
    int wv = (blockIdx.x * blockDim.x + threadIdx.x) >> 6;
    int lane = threadIdx.x & 63;
    if (wv >= NN) return;
    int start = rowptr[wv], end = rowptr[wv + 1];
    float a0 = 0.f, a1 = 0.f;
    for (int j = start; j < end; j += 64) {
        int myidx = (j + lane < end) ? esrc[j + lane] : 0;
        int cnt = min(64, end - j);
        for (int q = 0; q < cnt; ++q) {
            int s = __shfl(myidx, q);
            float2 v = *(const float2*)(x + (size_t)s * 128 + 2 * lane);
            a0 += v.x;
            a1 += v.y;
        }
    }
    float2 xv = *(const float2*)(x + (size_t)wv * 128 + 2 * lane);
    float2 o;
    o.x = xv.x + a0;
    o.y = xv.y + a1;
    *(float2*)(rst + (size_t)wv * 128 + 2 * lane) = o;
}

// ---------------- SPMM 40-wide with bias+self epilogue (final layer) ----------------
// out[v] = z[v] + b_out + sum_{in} z[src]
__global__ void spmm40_kernel(const float* __restrict__ z, const int* __restrict__ rowptr,
                              const int* __restrict__ esrc, const float* __restrict__ bout,
                              float* __restrict__ out) {
    int wv = (blockIdx.x * blockDim.x + threadIdx.x) >> 6;
    int lane = threadIdx.x & 63;
    if (wv >= NN) return;
    int start = rowptr[wv], end = rowptr[wv + 1];
    float a = 0.f;
    for (int j = start; j < end; j += 64) {
        int myidx = (j + lane < end) ? esrc[j + lane] : 0;
        int cnt = min(64, end - j);
        for (int q = 0; q < cnt; ++q) {
            int s = __shfl(myidx, q);
            // lanes 40..63 read past the 40-col row but stay inside the (larger) ws buffer
            a += z[(size_t)s * 40 + lane];
        }
    }
    if (lane < 40) {
        out[(size_t)wv * 40 + lane] = z[(size_t)wv * 40 + lane] + bout[lane] + a;
    }
}

// ---------------- GEMM: C[M][128] = A[M][128] @ W[128][128] + bias ----------------
__global__ __launch_bounds__(256) void gemm128_kernel(
    const float* __restrict__ A, const float* __restrict__ W,
    const float* __restrict__ bias, float* __restrict__ C, int M) {
    __shared__ float As[32][128];  // k-major
    __shared__ float Bs[32][128];
    const int t = threadIdx.x;
    const int br = blockIdx.x * 128;
    const int tm = (t >> 4) << 3;   // 0..120
    const int tn = (t & 15) << 3;   // 0..120
    const int lm = t & 127;
    const int lc0 = t >> 7;         // 0 or 1
    const int bk0 = t >> 5;         // 0..7
    const int bn = (t & 31) << 2;   // 0..124
    const int arow = min(br + lm, M - 1);
    const float* Ap = A + (size_t)arow * 128;

    float acc[8][8];
#pragma unroll
    for (int i = 0; i < 8; ++i)
#pragma unroll
        for (int j = 0; j < 8; ++j) acc[i][j] = 0.f;

    for (int k0 = 0; k0 < 128; k0 += 32) {
#pragma unroll
        for (int i = 0; i < 4; ++i) {
            int c = lc0 + 2 * i;  // 0..7
            float4 v = *(const float4*)(Ap + k0 + 4 * c);
            As[4 * c + 0][lm] = v.x;
            As[4 * c + 1][lm] = v.y;
            As[4 * c + 2][lm] = v.z;
            As[4 * c + 3][lm] = v.w;
        }
#pragma unroll
        for (int i = 0; i < 4; ++i) {
            int kk = bk0 + 8 * i;
            *(float4*)&Bs[kk][bn] = *(const float4*)(W + (size_t)(k0 + kk) * 128 + bn);
        }
        __syncthreads();
#pragma unroll
        for (int kk = 0; kk < 32; ++kk) {
            float a[8], b[8];
            *(float4*)&a[0] = *(const float4*)&As[kk][tm];
            *(float4*)&a[4] = *(const float4*)&As[kk][tm + 4];
            *(float4*)&b[0] = *(const float4*)&Bs[kk][tn];
            *(float4*)&b[4] = *(const float4*)&Bs[kk][tn + 4];
#pragma unroll
            for (int i = 0; i < 8; ++i)
#pragma unroll
                for (int j = 0; j < 8; ++j) acc[i][j] += a[i] * b[j];
        }
        __syncthreads();
    }
#pragma unroll
    for (int i = 0; i < 8; ++i) {
        int row = br + tm + i;
        if (row < M) {
            float4 o0, o1;
            o0.x = acc[i][0] + bias[tn + 0];
            o0.y = acc[i][1] + bias[tn + 1];
            o0.z = acc[i][2] + bias[tn + 2];
            o0.w = acc[i][3] + bias[tn + 3];
            o1.x = acc[i][4] + bias[tn + 4];
            o1.y = acc[i][5] + bias[tn + 5];
            o1.z = acc[i][6] + bias[tn + 6];
            o1.w = acc[i][7] + bias[tn + 7];
            *(float4*)(C + (size_t)row * 128 + tn) = o0;
            *(float4*)(C + (size_t)row * 128 + tn + 4) = o1;
        }
    }
}

// ---------------- GEMM: Z[M][40] = A[M][128] @ W[128][40] (no bias) ----------------
__global__ __launch_bounds__(256) void gemm40_kernel(
    const float* __restrict__ A, const float* __restrict__ W,
    float* __restrict__ Z, int M) {
    __shared__ float As[64][132];   // padded: aligned float4 + conflict-free
    __shared__ float Wls[128 * 40];
    const int t = threadIdx.x;
    const int br = blockIdx.x * 64;
#pragma unroll
    for (int i = 0; i < 5; ++i) {
        int idx = t + 256 * i;  // 1280 float4s
        *(float4*)&Wls[idx * 4] = *(const float4*)(W + idx * 4);
    }
    {
        int r = t >> 2;
        int row = min(br + r, M - 1);
        const float* Ap = A + (size_t)row * 128;
#pragma unroll
        for (int i = 0; i < 8; ++i) {
            int c = (t & 3) + 4 * i;  // 0..31
            float4 v = *(const float4*)(Ap + 4 * c);
            *(float4*)&As[r][4 * c] = v;
        }
    }
    __syncthreads();
    const int tm2 = (t >> 3) * 2;  // 0..62
    const int tn5 = (t & 7) * 5;   // 0..35
    float acc[2][5];
#pragma unroll
    for (int i = 0; i < 2; ++i)
#pragma unroll
        for (int j = 0; j < 5; ++j) acc[i][j] = 0.f;
#pragma unroll 4
    for (int kk = 0; kk < 128; ++kk) {
        float a0 = As[tm2][kk], a1 = As[tm2 + 1][kk];
#pragma unroll
        for (int j = 0; j < 5; ++j) {
            float b = Wls[kk * 40 + tn5 + j];
            acc[0][j] += a0 * b;
            acc[1][j] += a1 * b;
        }
    }
#pragma unroll
    for (int i = 0; i < 2; ++i) {
        int row = br + tm2 + i;
        if (row < M) {
#pragma unroll
            for (int j = 0; j < 5; ++j) Z[(size_t)row * 40 + tn5 + j] = acc[i][j];
        }
    }
}

extern "C" void kernel_launch(void* const* d_in, const int* in_sizes, int n_in,
                              void* d_out, int out_size, void* d_ws, size_t ws_size,
                              hipStream_t stream) {
    const float* h      = (const float*)d_in[0];
    const float* Ws     = (const float*)d_in[1];
    const float* bs     = (const float*)d_in[2];
    const float* W_out  = (const float*)d_in[3];
    const float* b_out  = (const float*)d_in[4];
    const int*   ei     = (const int*)d_in[5];   // int32 per harness convention
    float* out = (float*)d_out;

    char* p = (char*)d_ws;
    auto alloc = [&](size_t bytes) {
        char* r = p;
        p += (bytes + 255) & ~size_t(255);
        return r;
    };
    int* deg_cursor = (int*)alloc((size_t)NN * 4);        // deg, later cursor
    int* rowptr     = (int*)alloc((size_t)(NN + 1) * 4);
    int* bsums      = (int*)alloc(128 * 4);
    int* esrc       = (int*)alloc((size_t)NE * 4);
    float* R        = (float*)alloc((size_t)NN * 128 * 4); // rst / z buffer
    float* H        = (float*)alloc((size_t)NN * 128 * 4); // layer output

    // ---- CSR build (per call; ws is re-poisoned) ----
    hipMemsetAsync(deg_cursor, 0, (size_t)NN * 4, stream);
    hist_kernel<<<(NE + 255) / 256, 256, 0, stream>>>(ei, deg_cursor);
    int nb = (NN + 1023) / 1024;  // 98
    scan_partial<<<nb, 256, 0, stream>>>(deg_cursor, rowptr, bsums);
    scan_sums<<<1, 128, 0, stream>>>(bsums, nb);
    scan_finalize<<<(NN + 256) / 256, 256, 0, stream>>>(rowptr, bsums, rowptr, deg_cursor);
    fill_kernel<<<(NE + 255) / 256, 256, 0, stream>>>(ei, deg_cursor, esrc);

    // ---- layers 0..3: rst = x + seg_sum(x[src]); h = rst @ W + b ----
    const float* x = h;
    for (int l = 0; l < 4; ++l) {
        spmm128_kernel<<<NN / 4, 256, 0, stream>>>(x, rowptr, esrc, R);
        gemm128_kernel<<<(NN + 127) / 128, 256, 0, stream>>>(
            R, Ws + (size_t)l * 128 * 128, bs + (size_t)l * 128, H, NN);
        x = H;
    }
    // ---- layer 4 (linearity: GEMM first, then 40-wide aggregate) ----
    gemm40_kernel<<<(NN + 63) / 64, 256, 0, stream>>>(H, W_out, R, NN);
    spmm40_kernel<<<NN / 4, 256, 0, stream>>>(R, rowptr, esrc, b_out, out);
}

// Round 4
// 1064.496 us; speedup vs baseline: 1.0457x; 1.0457x over previous
//
#include <hip/hip_runtime.h>
#include <stdint.h>

#define NN 100000
#define NE 1600000

__device__ __forceinline__ void f4add(float4& a, const float4 v) {
    a.x += v.x; a.y += v.y; a.z += v.z; a.w += v.w;
}

// ---------------- CSR build ----------------
__global__ void hist_kernel(const int* __restrict__ ei, int* __restrict__ deg) {
    int e = blockIdx.x * blockDim.x + threadIdx.x;
    if (e >= NE) return;
    int d = ei[NE + e];
    atomicAdd(&deg[d], 1);
}

// per-block (1024 elems, 256 thr) exclusive scan; writes exclusive partials + block sums
__global__ void scan_partial(const int* __restrict__ deg, int* __restrict__ excl,
                             int* __restrict__ bsums) {
    __shared__ int ts[256];
    int t = threadIdx.x;
    int base = blockIdx.x * 1024 + t * 4;
    int v0 = 0, v1 = 0, v2 = 0, v3 = 0;
    if (base + 3 < NN) {
        int4 v = *(const int4*)(deg + base);
        v0 = v.x; v1 = v.y; v2 = v.z; v3 = v.w;
    } else {
        if (base + 0 < NN) v0 = deg[base + 0];
        if (base + 1 < NN) v1 = deg[base + 1];
        if (base + 2 < NN) v2 = deg[base + 2];
        if (base + 3 < NN) v3 = deg[base + 3];
    }
    int s3 = v0 + v1 + v2 + v3;
    ts[t] = s3;
    __syncthreads();
    int sum = s3;
    for (int off = 1; off < 256; off <<= 1) {
        int x = (t >= off) ? ts[t - off] : 0;
        __syncthreads();
        sum += x;
        ts[t] = sum;
        __syncthreads();
    }
    if (t == 255) bsums[blockIdx.x] = sum;
    int pre = sum - s3;  // exclusive over threads within block
    int e0 = pre, e1 = pre + v0, e2 = pre + v0 + v1, e3 = pre + v0 + v1 + v2;
    if (base + 3 < NN) {
        *(int4*)(excl + base) = make_int4(e0, e1, e2, e3);
    } else {
        if (base + 0 < NN) excl[base + 0] = e0;
        if (base + 1 < NN) excl[base + 1] = e1;
        if (base + 2 < NN) excl[base + 2] = e2;
        if (base + 3 < NN) excl[base + 3] = e3;
    }
}

__global__ void scan_sums(int* __restrict__ bsums, int nb) {  // 1 block, 128 thr
    __shared__ int ts[128];
    int t = threadIdx.x;
    int v = (t < nb) ? bsums[t] : 0;
    ts[t] = v;
    __syncthreads();
    int sum = v;
    for (int off = 1; off < 128; off <<= 1) {
        int x = (t >= off) ? ts[t - off] : 0;
        __syncthreads();
        sum += x;
        ts[t] = sum;
        __syncthreads();
    }
    if (t < nb) bsums[t] = sum - v;  // exclusive
}

__global__ void scan_finalize(const int* __restrict__ excl, const int* __restrict__ bsums,
                              int* __restrict__ rowptr, int* __restrict__ cursor) {
    int i = blockIdx.x * blockDim.x + threadIdx.x;
    if (i < NN) {
        int v = excl[i] + bsums[i >> 10];
        rowptr[i] = v;
        cursor[i] = v;
    } else if (i == NN) {
        rowptr[NN] = NE;
    }
}

__global__ void fill_kernel(const int* __restrict__ ei, int* __restrict__ cursor,
                            int* __restrict__ esrc) {
    int e = blockIdx.x * blockDim.x + threadIdx.x;
    if (e >= NE) return;
    int s = ei[e];
    int d = ei[NE + e];
    int pos = atomicAdd(&cursor[d], 1);
    esrc[pos] = s;
}

// ---------------- SPMM (segment sum), 128-wide rows ----------------
// 16-lane group per node (4 nodes/wave = 4 independent gather streams);
// lane covers 8 cols (2x float4); edge loop unrolled x2 for MLP.
__global__ __launch_bounds__(256) void spmm128_kernel(
    const float* __restrict__ x, const int* __restrict__ rowptr,
    const int* __restrict__ esrc, float* __restrict__ rst) {
    int grp = (blockIdx.x * blockDim.x + threadIdx.x) >> 4;
    if (grp >= NN) return;
    const int sub = threadIdx.x & 15;
    const int gbase = threadIdx.x & 48;  // group's base lane within the wave
    const size_t coff = (size_t)sub * 8;
    int start = rowptr[grp], end = rowptr[grp + 1];
    float4 a0 = make_float4(0.f, 0.f, 0.f, 0.f);
    float4 a1 = make_float4(0.f, 0.f, 0.f, 0.f);
    for (int j = start; j < end; j += 16) {
        int myidx = (j + sub < end) ? esrc[j + sub] : 0;
        int cnt = min(16, end - j);
        int q = 0;
        for (; q + 2 <= cnt; q += 2) {
            int s0 = __shfl(myidx, gbase + q);
            int s1 = __shfl(myidx, gbase + q + 1);
            const float* r0 = x + (size_t)s0 * 128 + coff;
            const float* r1 = x + (size_t)s1 * 128 + coff;
            float4 v00 = *(const float4*)r0;
            float4 v01 = *(const float4*)(r0 + 4);
            float4 v10 = *(const float4*)r1;
            float4 v11 = *(const float4*)(r1 + 4);
            f4add(a0, v00); f4add(a1, v01);
            f4add(a0, v10); f4add(a1, v11);
        }
        if (q < cnt) {
            int s0 = __shfl(myidx, gbase + q);
            const float* r0 = x + (size_t)s0 * 128 + coff;
            f4add(a0, *(const float4*)r0);
            f4add(a1, *(const float4*)(r0 + 4));
        }
    }
    const float* xs = x + (size_t)grp * 128 + coff;
    f4add(a0, *(const float4*)xs);
    f4add(a1, *(const float4*)(xs + 4));
    float* rp = rst + (size_t)grp * 128 + coff;
    *(float4*)rp = a0;
    *(float4*)(rp + 4) = a1;
}

// ---------------- SPMM 40-wide with bias+self epilogue (final layer) ----------------
// out[v] = z[v] + b_out + sum_{in} z[src]; 16-lane group per node, 10 data lanes.
__global__ __launch_bounds__(256) void spmm40_kernel(
    const float* __restrict__ z, const int* __restrict__ rowptr,
    const int* __restrict__ esrc, const float* __restrict__ bout,
    float* __restrict__ out) {
    int grp = (blockIdx.x * blockDim.x + threadIdx.x) >> 4;
    if (grp >= NN) return;
    const int sub = threadIdx.x & 15;
    const int gbase = threadIdx.x & 48;
    const int c4 = sub * 4;  // cols; only sub<10 meaningful (lanes 10-15 read slack in ws)
    int start = rowptr[grp], end = rowptr[grp + 1];
    float4 a = make_float4(0.f, 0.f, 0.f, 0.f);
    for (int j = start; j < end; j += 16) {
        int myidx = (j + sub < end) ? esrc[j + sub] : 0;
        int cnt = min(16, end - j);
        int q = 0;
        for (; q + 2 <= cnt; q += 2) {
            int s0 = __shfl(myidx, gbase + q);
            int s1 = __shfl(myidx, gbase + q + 1);
            float4 v0 = *(const float4*)(z + (size_t)s0 * 40 + c4);
            float4 v1 = *(const float4*)(z + (size_t)s1 * 40 + c4);
            f4add(a, v0);
            f4add(a, v1);
        }
        if (q < cnt) {
            int s0 = __shfl(myidx, gbase + q);
            f4add(a, *(const float4*)(z + (size_t)s0 * 40 + c4));
        }
    }
    if (sub < 10) {
        float4 self = *(const float4*)(z + (size_t)grp * 40 + c4);
        float4 bb = *(const float4*)(bout + c4);
        float4 o;
        o.x = self.x + bb.x + a.x;
        o.y = self.y + bb.y + a.y;
        o.z = self.z + bb.z + a.z;
        o.w = self.w + bb.w + a.w;
        *(float4*)(out + (size_t)grp * 40 + c4) = o;
    }
}

// ---------------- GEMM: C[M][128] = A[M][128] @ W[128][128] + bias ----------------
__global__ __launch_bounds__(256) void gemm128_kernel(
    const float* __restrict__ A, const float* __restrict__ W,
    const float* __restrict__ bias, float* __restrict__ C, int M) {
    __shared__ float As[32][128];  // k-major
    __shared__ float Bs[32][128];
    const int t = threadIdx.x;
    const int br = blockIdx.x * 128;
    const int tm = (t >> 4) << 3;   // 0..120
    const int tn = (t & 15) << 3;   // 0..120
    const int lm = t & 127;
    const int lc0 = t >> 7;         // 0 or 1
    const int bk0 = t >> 5;         // 0..7
    const int bn = (t & 31) << 2;   // 0..124
    const int arow = min(br + lm, M - 1);
    const float* Ap = A + (size_t)arow * 128;

    float acc[8][8];
#pragma unroll
    for (int i = 0; i < 8; ++i)
#pragma unroll
        for (int j = 0; j < 8; ++j) acc[i][j] = 0.f;

    for (int k0 = 0; k0 < 128; k0 += 32) {
#pragma unroll
        for (int i = 0; i < 4; ++i) {
            int c = lc0 + 2 * i;  // 0..7
            float4 v = *(const float4*)(Ap + k0 + 4 * c);
            As[4 * c + 0][lm] = v.x;
            As[4 * c + 1][lm] = v.y;
            As[4 * c + 2][lm] = v.z;
            As[4 * c + 3][lm] = v.w;
        }
#pragma unroll
        for (int i = 0; i < 4; ++i) {
            int kk = bk0 + 8 * i;
            *(float4*)&Bs[kk][bn] = *(const float4*)(W + (size_t)(k0 + kk) * 128 + bn);
        }
        __syncthreads();
#pragma unroll
        for (int kk = 0; kk < 32; ++kk) {
            float a[8], b[8];
            *(float4*)&a[0] = *(const float4*)&As[kk][tm];
            *(float4*)&a[4] = *(const float4*)&As[kk][tm + 4];
            *(float4*)&b[0] = *(const float4*)&Bs[kk][tn];
            *(float4*)&b[4] = *(const float4*)&Bs[kk][tn + 4];
#pragma unroll
            for (int i = 0; i < 8; ++i)
#pragma unroll
                for (int j = 0; j < 8; ++j) acc[i][j] += a[i] * b[j];
        }
        __syncthreads();
    }
#pragma unroll
    for (int i = 0; i < 8; ++i) {
        int row = br + tm + i;
        if (row < M) {
            float4 o0, o1;
            o0.x = acc[i][0] + bias[tn + 0];
            o0.y = acc[i][1] + bias[tn + 1];
            o0.z = acc[i][2] + bias[tn + 2];
            o0.w = acc[i][3] + bias[tn + 3];
            o1.x = acc[i][4] + bias[tn + 4];
            o1.y = acc[i][5] + bias[tn + 5];
            o1.z = acc[i][6] + bias[tn + 6];
            o1.w = acc[i][7] + bias[tn + 7];
            *(float4*)(C + (size_t)row * 128 + tn) = o0;
            *(float4*)(C + (size_t)row * 128 + tn + 4) = o1;
        }
    }
}

// ---------------- GEMM: Z[M][40] = A[M][128] @ W[128][40] (no bias) ----------------
__global__ __launch_bounds__(256) void gemm40_kernel(
    const float* __restrict__ A, const float* __restrict__ W,
    float* __restrict__ Z, int M) {
    __shared__ float As[64][132];   // padded: aligned float4 + conflict-free
    __shared__ float Wls[128 * 40];
    const int t = threadIdx.x;
    const int br = blockIdx.x * 64;
#pragma unroll
    for (int i = 0; i < 5; ++i) {
        int idx = t + 256 * i;  // 1280 float4s
        *(float4*)&Wls[idx * 4] = *(const float4*)(W + idx * 4);
    }
    {
        int r = t >> 2;
        int row = min(br + r, M - 1);
        const float* Ap = A + (size_t)row * 128;
#pragma unroll
        for (int i = 0; i < 8; ++i) {
            int c = (t & 3) + 4 * i;  // 0..31
            float4 v = *(const float4*)(Ap + 4 * c);
            *(float4*)&As[r][4 * c] = v;
        }
    }
    __syncthreads();
    const int tm2 = (t >> 3) * 2;  // 0..62
    const int tn5 = (t & 7) * 5;   // 0..35
    float acc[2][5];
#pragma unroll
    for (int i = 0; i < 2; ++i)
#pragma unroll
        for (int j = 0; j < 5; ++j) acc[i][j] = 0.f;
#pragma unroll 4
    for (int kk = 0; kk < 128; ++kk) {
        float a0 = As[tm2][kk], a1 = As[tm2 + 1][kk];
#pragma unroll
        for (int j = 0; j < 5; ++j) {
            float b = Wls[kk * 40 + tn5 + j];
            acc[0][j] += a0 * b;
            acc[1][j] += a1 * b;
        }
    }
#pragma unroll
    for (int i = 0; i < 2; ++i) {
        int row = br + tm2 + i;
        if (row < M) {
#pragma unroll
            for (int j = 0; j < 5; ++j) Z[(size_t)row * 40 + tn5 + j] = acc[i][j];
        }
    }
}

extern "C" void kernel_launch(void* const* d_in, const int* in_sizes, int n_in,
                              void* d_out, int out_size, void* d_ws, size_t ws_size,
                              hipStream_t stream) {
    const float* h      = (const float*)d_in[0];
    const float* Ws     = (const float*)d_in[1];
    const float* bs     = (const float*)d_in[2];
    const float* W_out  = (const float*)d_in[3];
    const float* b_out  = (const float*)d_in[4];
    const int*   ei     = (const int*)d_in[5];   // int32 per harness convention
    float* out = (float*)d_out;

    char* p = (char*)d_ws;
    auto alloc = [&](size_t bytes) {
        char* r = p;
        p += (bytes + 255) & ~size_t(255);
        return r;
    };
    int* deg_cursor = (int*)alloc((size_t)NN * 4);        // deg, later cursor
    int* rowptr     = (int*)alloc((size_t)(NN + 1) * 4);
    int* bsums      = (int*)alloc(128 * 4);
    int* esrc       = (int*)alloc((size_t)NE * 4);
    float* R        = (float*)alloc((size_t)NN * 128 * 4); // rst / z buffer
    float* H        = (float*)alloc((size_t)NN * 128 * 4); // layer output

    // ---- CSR build (per call; ws is re-poisoned) ----
    hipMemsetAsync(deg_cursor, 0, (size_t)NN * 4, stream);
    hist_kernel<<<(NE + 255) / 256, 256, 0, stream>>>(ei, deg_cursor);
    int nb = (NN + 1023) / 1024;  // 98
    scan_partial<<<nb, 256, 0, stream>>>(deg_cursor, rowptr, bsums);
    scan_sums<<<1, 128, 0, stream>>>(bsums, nb);
    scan_finalize<<<(NN + 256) / 256, 256, 0, stream>>>(rowptr, bsums, rowptr, deg_cursor);
    fill_kernel<<<(NE + 255) / 256, 256, 0, stream>>>(ei, deg_cursor, esrc);

    // ---- layers 0..3: rst = x + seg_sum(x[src]); h = rst @ W + b ----
    const int spmm_grid = (NN * 16 + 255) / 256;  // 16 lanes per node
    const float* x = h;
    for (int l = 0; l < 4; ++l) {
        spmm128_kernel<<<spmm_grid, 256, 0, stream>>>(x, rowptr, esrc, R);
        gemm128_kernel<<<(NN + 127) / 128, 256, 0, stream>>>(
            R, Ws + (size_t)l * 128 * 128, bs + (size_t)l * 128, H, NN);
        x = H;
    }
    // ---- layer 4 (linearity: GEMM first, then 40-wide aggregate) ----
    gemm40_kernel<<<(NN + 63) / 64, 256, 0, stream>>>(H, W_out, R, NN);
    spmm40_kernel<<<spmm_grid, 256, 0, stream>>>(R, rowptr, esrc, b_out, out);
}